// Round 10
// baseline (552.900 us; speedup 1.0000x reference)
//
#include <hip/hip_runtime.h>
#include <cstdint>

#define M_DIM 8192
#define K_DIM 4096
#define N_DIM 12288
#define KT 32  // K-tiles of BK=128 int8

using i32x4 = __attribute__((ext_vector_type(4))) int;

__device__ inline void gload_lds16(const void* g, void* l) {
    __builtin_amdgcn_global_load_lds(
        (const __attribute__((address_space(1))) void*)g,
        (__attribute__((address_space(3))) void*)l,
        16, 0, 0);
}

__device__ inline int pack4(int4 v) {
    return (v.x & 255) | ((v.y & 255) << 8) | ((v.z & 255) << 16) | (v.w << 24);
}

// ---- fused: per-row quant (blocks 0..M-1) + weight repack into per-wave-tiled B' ----
// B' granule layout (16 B units): idx = ((((bn*4+wn)*32 + j)*4 + nf)*2 + ks)*64
//                                        + lk*16 + lr
// holding int8 of B[n= bn*256+wn*64+nf*16+lr][k = j*128 + (ks*4+lk)*16 .. +16)
__global__ __launch_bounds__(256) void quant_pack(const float* __restrict__ x,
                                                  const int* __restrict__ w32,
                                                  int8_t* __restrict__ qa,
                                                  float* __restrict__ ascale,
                                                  int8_t* __restrict__ wb) {
    const int t = threadIdx.x;
    if (blockIdx.x < M_DIM) {
        const int row = blockIdx.x;
        const float4* xr = (const float4*)(x + (size_t)row * K_DIM);
        float4 v[4];
        float amax = 0.0f;
#pragma unroll
        for (int c = 0; c < 4; ++c) {
            v[c] = xr[t + 256 * c];
            amax = fmaxf(amax, fmaxf(fmaxf(fabsf(v[c].x), fabsf(v[c].y)),
                                     fmaxf(fabsf(v[c].z), fabsf(v[c].w))));
        }
#pragma unroll
        for (int off = 32; off > 0; off >>= 1)
            amax = fmaxf(amax, __shfl_xor(amax, off));
        __shared__ float smax[4];
        if ((t & 63) == 0) smax[t >> 6] = amax;
        __syncthreads();
        amax = fmaxf(fmaxf(smax[0], smax[1]), fmaxf(smax[2], smax[3]));
        const float sc = amax * (1.0f / 127.0f);
        const float inv = (amax > 0.0f) ? (127.0f / amax) : 0.0f;
        if (t == 0) ascale[row] = sc;

        int* q32 = (int*)(qa + (size_t)row * K_DIM);
#pragma unroll
        for (int c = 0; c < 4; ++c) {
            int q0 = (int)rintf(v[c].x * inv);
            int q1 = (int)rintf(v[c].y * inv);
            int q2 = (int)rintf(v[c].z * inv);
            int q3 = (int)rintf(v[c].w * inv);
            q0 = min(127, max(-128, q0));
            q1 = min(127, max(-128, q1));
            q2 = min(127, max(-128, q2));
            q3 = min(127, max(-128, q3));
            q32[t + 256 * c] = (q0 & 255) | ((q1 & 255) << 8) | ((q2 & 255) << 16) | (q3 << 24);
        }
    } else {
        const int pb = blockIdx.x - M_DIM;  // 0..2047
        const size_t total = (size_t)N_DIM * K_DIM / 16;  // 16B granules
        const size_t stride = (size_t)2048 * 256;
        for (size_t i = (size_t)pb * 256 + t; i < total; i += stride) {
            const uint32_t c = (uint32_t)i;
            const int lr = c & 15;
            const int lk = (c >> 4) & 3;
            const uint32_t q = c >> 6;
            const int ks = q & 1;
            const int nf = (q >> 1) & 3;
            const uint32_t r = q >> 3;
            const int j = r & 31;
            const uint32_t s2 = r >> 5;           // bn*4 + wn
            const int n = (int)(s2 >> 2) * 256 + (int)(s2 & 3) * 64 + nf * 16 + lr;
            const int k0 = j * 128 + (ks * 4 + lk) * 16;
            const int4* src = (const int4*)(w32 + (size_t)n * K_DIM + k0);
            const int4 v0 = src[0], v1 = src[1], v2 = src[2], v3 = src[3];
            i32x4 o;
            o[0] = pack4(v0); o[1] = pack4(v1); o[2] = pack4(v2); o[3] = pack4(v3);
            ((i32x4*)wb)[i] = o;
        }
    }
}

// ---- int8 GEMM: 256x256, BK=128, A in dbuf LDS, B global->reg, 1 barrier/K-tile ----
__global__ __launch_bounds__(512, 2) void gemm_i8(const int8_t* __restrict__ qa,
                                                  const int8_t* __restrict__ wb,
                                                  const float* __restrict__ ascale,
                                                  const float* __restrict__ wscale,
                                                  const float* __restrict__ bias,
                                                  float* __restrict__ out) {
    __shared__ int8_t lds[2][32768];  // A only: [slot][256 rows x 128 B] = 64 KiB

    const int t = threadIdx.x;
    const int lane = t & 63;
    const int wave = t >> 6;       // 0..7
    const int wm = wave >> 2;      // 0..1 -> 128 rows of A
    const int wn = wave & 3;       // 0..3 -> 64 cols of C
    const int lrow = lane & 15;
    const int lk = lane >> 4;      // 0..3
    const int sw7 = lrow & 7;      // read-side XOR swizzle (A)

    // XCD-aware bijective swizzle: 1536 = 8 * 192
    const int flat = blockIdx.x;
    const int sw = (flat & 7) * 192 + (flat >> 3);
    const int bm = sw / 48;  // 0..31
    const int bn = sw % 48;  // 0..47

    // A staging: linear LDS dest; global k-slot permuted by the reader's involution
    const int srow = t >> 3;             // 0..63
    const int g = (t & 7) ^ (srow & 7);

#define STAGE_A(sb, jt)                                                        \
    {                                                                          \
        _Pragma("unroll") for (int c = 0; c < 4; ++c)                          \
            gload_lds16(qa + (size_t)(bm * 256 + srow + 64 * c) * K_DIM +      \
                            (size_t)g * 16 + (size_t)(jt) * 128,               \
                        &lds[sb][c * 8192 + t * 16]);                          \
    }
#define READ_A(dst, cs, mh)                                                    \
    {                                                                          \
        _Pragma("unroll") for (int mf = 0; mf < 4; ++mf)                       \
            _Pragma("unroll") for (int ks = 0; ks < 2; ++ks)                   \
                dst[mf][ks] = *(const i32x4*)&lds[cs][(wm * 128 + (mh)*64 +    \
                                                      mf * 16 + lrow) * 128 + \
                                                     ((((ks << 2) | lk) ^ sw7) << 4)]; \
    }
    // B': per-wave contiguous 1KB chunks; chunk (nf*2+ks) at tile j.
    const int8_t* wbase = wb + (size_t)(bn * 4 + wn) * 262144 + (size_t)lane * 16;
#define LOAD_BLO(jt)                                                           \
    {                                                                          \
        _Pragma("unroll") for (int nf = 0; nf < 2; ++nf)                       \
            _Pragma("unroll") for (int ks = 0; ks < 2; ++ks)                   \
                bLo[nf][ks] = *(const i32x4*)(wbase + (size_t)(jt)*8192 +      \
                                              (nf * 2 + ks) * 1024);           \
    }
#define LOAD_BHI(jt)                                                           \
    {                                                                          \
        _Pragma("unroll") for (int nf = 0; nf < 2; ++nf)                       \
            _Pragma("unroll") for (int ks = 0; ks < 2; ++ks)                   \
                bHi[nf][ks] = *(const i32x4*)(wbase + (size_t)(jt)*8192 +      \
                                              ((nf + 2) * 2 + ks) * 1024);     \
    }
#define MM8(AH, mb, BH, nb)                                                    \
    {                                                                          \
        __builtin_amdgcn_s_setprio(1);                                         \
        _Pragma("unroll") for (int ks = 0; ks < 2; ++ks)                       \
            _Pragma("unroll") for (int mf = 0; mf < 4; ++mf)                   \
                _Pragma("unroll") for (int nf = 0; nf < 2; ++nf)               \
                    acc[(mb) + mf][(nb) + nf] =                                \
                        __builtin_amdgcn_mfma_i32_16x16x64_i8(                 \
                            AH[mf][ks], BH[nf][ks],                            \
                            acc[(mb) + mf][(nb) + nf], 0, 0, 0);               \
        __builtin_amdgcn_s_setprio(0);                                         \
    }
#define SB0 __builtin_amdgcn_sched_barrier(0);
#define BAR __builtin_amdgcn_s_barrier();
#define WAIT_LGKM(n) asm volatile("s_waitcnt lgkmcnt(" #n ")" ::: "memory");
#define WAIT_VM(n) asm volatile("s_waitcnt vmcnt(" #n ")" ::: "memory");

    i32x4 acc[8][4] = {};
    i32x4 a0[4][2], a1[4][2], bLo[2][2], bHi[2][2];

    // prologue: stage A(0) (4 gload_lds), load B(0) (8 global loads)
    STAGE_A(0, 0);
    LOAD_BLO(0);
    LOAD_BHI(0);
    SB0;

    for (int j = 0; j < KT; ++j) {
        const int cs = j & 1;
        const int ns = cs ^ 1;

        // tile start: own A(j)-slice + bLo(j) landed [leaves bHi(j) (+older none)]
        WAIT_VM(4);
        SB0;
        BAR;  // all waves' A(j) slices in LDS; all prev-tile reads retired
        SB0;
        if (j + 1 < KT) STAGE_A(ns, j + 1);  // 4 gload_lds -> slot ns
        READ_A(a0, cs, 0);                   // 8 ds_reads
        READ_A(a1, cs, 1);                   // 8 ds_reads
        SB0;
        WAIT_LGKM(8);  // a0 done, a1 in flight
        SB0;
        MM8(a0, 0, bLo, 0);  // ph0
        WAIT_LGKM(0);        // a1 drained under ph0
        SB0;
        MM8(a1, 4, bLo, 0);  // ph1 (bLo dead after)
        if (j + 1 < KT) {
            LOAD_BLO(j + 1);  // 4 loads into bLo (disjoint live range)
            SB0;
            WAIT_VM(8);  // bHi(j) landed [leaves A(j+1), bLo(j+1)]
        } else {
            WAIT_VM(0);  // bHi(j) landed
        }
        SB0;
        MM8(a1, 4, bHi, 2);  // ph2
        MM8(a0, 0, bHi, 2);  // ph3 (bHi dead after)
        if (j + 1 < KT) LOAD_BHI(j + 1);  // 4 loads; needed at ph2(j+1)
        SB0;
    }

    // epilogue: C/D layout col = lane&15, row = (lane>>4)*4 + j
    const int r0 = bm * 256 + wm * 128;
    const int c0 = bn * 256 + wn * 64;
    float asc[8][4];
#pragma unroll
    for (int m = 0; m < 8; ++m)
#pragma unroll
        for (int jj = 0; jj < 4; ++jj)
            asc[m][jj] = ascale[r0 + m * 16 + lk * 4 + jj];
#pragma unroll
    for (int n = 0; n < 4; ++n) {
        const int col = c0 + n * 16 + lrow;
        const float wsc = wscale[col];
        const float bb = bias[col];
#pragma unroll
        for (int m = 0; m < 8; ++m) {
#pragma unroll
            for (int jj = 0; jj < 4; ++jj) {
                const int row = r0 + m * 16 + lk * 4 + jj;
                out[(size_t)row * N_DIM + col] = (float)acc[m][n][jj] * asc[m][jj] * wsc + bb;
            }
        }
    }
}

extern "C" void kernel_launch(void* const* d_in, const int* in_sizes, int n_in,
                              void* d_out, int out_size, void* d_ws, size_t ws_size,
                              hipStream_t stream) {
    const float* x = (const float*)d_in[0];
    const int* w32 = (const int*)d_in[1];  // int8 weights arrive as int32
    const float* wscale = (const float*)d_in[2];
    const float* bias = (const float*)d_in[3];
    float* out = (float*)d_out;

    int8_t* qa = (int8_t*)d_ws;                                     // M*K int8
    float* ascale = (float*)((char*)d_ws + (size_t)M_DIM * K_DIM);  // M f32
    int8_t* wb = (int8_t*)((char*)d_ws + (size_t)M_DIM * K_DIM +
                           (size_t)M_DIM * sizeof(float));          // N*K int8 (tiled B')

    quant_pack<<<M_DIM + 2048, 256, 0, stream>>>(x, w32, qa, ascale, wb);
    gemm_i8<<<1536, 512, 0, stream>>>(qa, wb, ascale, wscale, bias, out);
}